// Round 1
// baseline (134.531 us; speedup 1.0000x reference)
//
#include <hip/hip_runtime.h>

typedef short v8s __attribute__((ext_vector_type(8)));
typedef short v4s __attribute__((ext_vector_type(4)));
typedef float v16f __attribute__((ext_vector_type(16)));

// RNE float -> bf16 (matches qtorch float_quantize(exp=8, man=7) semantics for
// normal-range inputs: round-half-to-even on the 8-bit mantissa, carry bumps
// exponent correctly; no subnormal/saturation cases arise for these inputs).
__device__ __forceinline__ unsigned short rne_bf16(float f) {
  unsigned u = __float_as_uint(f);
  return (unsigned short)((u + 0x7fffu + ((u >> 16) & 1u)) >> 16);
}

// ---------------------------------------------------------------------------
// prep_x: x[b][c][h][w] fp32 -> Xp[b][h+1][w+1][c] bf16 (padded 58x58, NHWC)
// One block per (b,h). LDS transpose so global reads AND writes are coalesced.
// Also zeroes the pad borders (harness re-poisons ws every launch).
// ---------------------------------------------------------------------------
__global__ __launch_bounds__(256) void prep_x(const float* __restrict__ x,
                                              unsigned short* __restrict__ Xp) {
  int bh = blockIdx.x;
  int b = bh / 56, h = bh % 56;
  __shared__ unsigned short tile[56 * 72];  // [w][c], c-stride 72 to spread banks
  int tid = threadIdx.x;

  // border columns (w=0 and w=57) of this row
  unsigned short* rowp = Xp + (((size_t)b * 58 + (h + 1)) * 58) * 64;
  if (tid < 64) { rowp[tid] = 0; rowp[57 * 64 + tid] = 0; }
  // border rows 0 and 57 (done by the h==0 block of each batch)
  if (h == 0) {
    unsigned short* r0 = Xp + ((size_t)b * 58 * 58) * 64;
    unsigned short* r57 = r0 + (size_t)57 * 58 * 64;
    for (int i = tid; i < 58 * 64; i += 256) { r0[i] = 0; r57[i] = 0; }
  }

  // phase 1: coalesced read along w, pack 4 channels, write LDS [w][c]
  if (tid < 224) {
    int cg = tid / 56;       // 0..3
    int w = tid % 56;
    const float* xb = x + (((size_t)b * 64) * 56 + h) * 56 + w;  // c stride 3136
#pragma unroll
    for (int r = 0; r < 4; ++r) {
      int c0 = cg * 16 + r * 4;
      float v0 = xb[(size_t)(c0 + 0) * 3136];
      float v1 = xb[(size_t)(c0 + 1) * 3136];
      float v2 = xb[(size_t)(c0 + 2) * 3136];
      float v3 = xb[(size_t)(c0 + 3) * 3136];
      v4s pk;
      pk.x = (short)rne_bf16(v0);
      pk.y = (short)rne_bf16(v1);
      pk.z = (short)rne_bf16(v2);
      pk.w = (short)rne_bf16(v3);
      *(v4s*)&tile[w * 72 + c0] = pk;
    }
  }
  __syncthreads();

  // phase 2: write interior, 128 B contiguous per w, w contiguous -> long runs
  unsigned short* dst = Xp + (((size_t)b * 58 + (h + 1)) * 58 + 1) * 64;
  for (int i = tid; i < 448; i += 256) {  // 56 w * 8 chan-blocks
    int w = i >> 3, cb = i & 7;
    *(v8s*)&dst[w * 64 + cb * 8] = *(const v8s*)&tile[w * 72 + cb * 8];
  }
}

// ---------------------------------------------------------------------------
// prep_w: w[n][c][kh][kw] fp32 -> Wt[pos][n][c] bf16   (pos = kh*3+kw)
// ---------------------------------------------------------------------------
__global__ __launch_bounds__(256) void prep_w(const float* __restrict__ w,
                                              unsigned short* __restrict__ Wt) {
  int t = blockIdx.x * 256 + threadIdx.x;  // 0..8191 = n*64 + c
  if (t >= 8192) return;
  const float* src = w + (size_t)t * 9;
#pragma unroll
  for (int pos = 0; pos < 9; ++pos) Wt[pos * 8192 + t] = rne_bf16(src[pos]);
}

// ---------------------------------------------------------------------------
// conv_main: implicit GEMM. Grid 896 = 32 b * 14 row-quads * 2 col-halves.
// WG tile: 128 ch x (4 rows x 32 cols, 28 valid). Wave = 64ch x 64sp quadrant.
// Input tile in LDS (CS=72 pad: 16B-aligned, uniform bank spread).
// W fragments straight from global (147 KB total -> L1/L2 resident).
// ---------------------------------------------------------------------------
#define CS 72

__global__ __launch_bounds__(256) void conv_main(const unsigned short* __restrict__ Xp,
                                                 const unsigned short* __restrict__ Wt,
                                                 const float* __restrict__ bias,
                                                 float* __restrict__ out) {
  __shared__ unsigned short xs[6 * 34 * CS];
  __shared__ float qb[128];

  int blk = blockIdx.x;
  int half = blk & 1;
  int t2 = blk >> 1;
  int rq = t2 % 14, b = t2 / 14;
  int oh0 = rq * 4, ow0 = half * 28;

  int tid = threadIdx.x;
  if (tid < 128) qb[tid] = __uint_as_float(((unsigned)rne_bf16(bias[tid])) << 16);

  // stage input tile: Xp rows oh0..oh0+5, cols ow0..ow0+29, all 64 ch
  const unsigned short* xpb = Xp + (((size_t)b * 58 + oh0) * 58 + ow0) * 64;
  for (int i = tid; i < 1440; i += 256) {  // 6*30 positions * 8 chan-blocks
    int cb = i & 7;
    int p = i >> 3;
    int col = p % 30, row = p / 30;
    *(v8s*)&xs[(row * 34 + col) * CS + cb * 8] =
        *(const v8s*)&xpb[(row * 58 + col) * 64 + cb * 8];
  }
  __syncthreads();

  int wv = tid >> 6, lane = tid & 63;
  int lj = lane & 31, lh = lane >> 5;
  int ct0 = (wv >> 1) * 2;  // ch-tile pair base (0 or 2): ch = (ct0+ct)*32 + ...
  int st0 = (wv & 1) * 2;   // output-row pair base (0 or 2)

  v16f acc[2][2];
#pragma unroll
  for (int a = 0; a < 2; ++a)
#pragma unroll
    for (int s = 0; s < 2; ++s)
#pragma unroll
      for (int e = 0; e < 16; ++e) acc[a][s][e] = 0.0f;

  // A-operand (W): lane holds W[ch = lane&31][c = 8*(lane>>5) + r]
  int wBase = ct0 * 2048 + lj * 64 + lh * 8;
  // B-operand (patches): lane holds P[c = 8*(lane>>5)+r][sp = lane&31]
#pragma unroll 1
  for (int kh = 0; kh < 3; ++kh) {
#pragma unroll
    for (int kw = 0; kw < 3; ++kw) {
      int pos = kh * 3 + kw;
      const unsigned short* wp = Wt + pos * 8192 + wBase;
      const unsigned short* pp = &xs[((st0 + kh) * 34 + kw + lj) * CS + lh * 8];
#pragma unroll
      for (int kk = 0; kk < 4; ++kk) {
        v8s wf0 = *(const v8s*)(wp + kk * 16);
        v8s wf1 = *(const v8s*)(wp + 2048 + kk * 16);
        v8s pf0 = *(const v8s*)(pp + kk * 16);
        v8s pf1 = *(const v8s*)(pp + 34 * CS + kk * 16);
        acc[0][0] = __builtin_amdgcn_mfma_f32_32x32x16_bf16(wf0, pf0, acc[0][0], 0, 0, 0);
        acc[0][1] = __builtin_amdgcn_mfma_f32_32x32x16_bf16(wf0, pf1, acc[0][1], 0, 0, 0);
        acc[1][0] = __builtin_amdgcn_mfma_f32_32x32x16_bf16(wf1, pf0, acc[1][0], 0, 0, 0);
        acc[1][1] = __builtin_amdgcn_mfma_f32_32x32x16_bf16(wf1, pf1, acc[1][1], 0, 0, 0);
      }
    }
  }

  // epilogue: C/D layout col=lane&31 (=ow offset), row=(r&3)+8*(r>>2)+4*lh (=ch)
  int ow = ow0 + lj;
  if (lj < 28) {
#pragma unroll
    for (int ct = 0; ct < 2; ++ct) {
#pragma unroll
      for (int st = 0; st < 2; ++st) {
        int orow = oh0 + st0 + st;
#pragma unroll
        for (int r = 0; r < 16; ++r) {
          int ch = (ct0 + ct) * 32 + (r & 3) + 8 * (r >> 2) + 4 * lh;
          out[(((size_t)b * 128 + ch) * 56 + orow) * 56 + ow] = acc[ct][st][r] + qb[ch];
        }
      }
    }
  }
}

extern "C" void kernel_launch(void* const* d_in, const int* in_sizes, int n_in,
                              void* d_out, int out_size, void* d_ws, size_t ws_size,
                              hipStream_t stream) {
  const float* x = (const float*)d_in[0];     // [32,64,56,56]
  const float* w = (const float*)d_in[1];     // [128,64,3,3]
  const float* bias = (const float*)d_in[2];  // [128]
  float* out = (float*)d_out;                 // [32,128,56,56] fp32

  unsigned short* Xp = (unsigned short*)d_ws;              // 32*58*58*64 bf16
  const size_t XP_BYTES = (size_t)32 * 58 * 58 * 64 * 2;   // 13,778,944 B
  unsigned short* Wt = (unsigned short*)((char*)d_ws + XP_BYTES);  // 9*128*64 bf16

  prep_x<<<32 * 56, 256, 0, stream>>>(x, Xp);
  prep_w<<<32, 256, 0, stream>>>(w, Wt);
  conv_main<<<896, 256, 0, stream>>>(Xp, Wt, bias, out);
}